// Round 1
// baseline (617.414 us; speedup 1.0000x reference)
//
#include <hip/hip_runtime.h>

// GCN 2-layer forward for MI355X.
// Layer: out[v] = dinv[v] * ( hs[v] + sum_{e: dst=v} hs[src_e] ) + b,
// where hs[u] = (x @ W)[u] * dinv[u], dinv = rsqrt(1 + indeg).

#define C_HID 64   // both hidden and output channel counts are 64

static inline size_t alignup(size_t x) { return (x + 255) & ~(size_t)255; }

__global__ void init_deg_kernel(float* __restrict__ deg, int n) {
    int i = blockIdx.x * blockDim.x + threadIdx.x;
    if (i < n) deg[i] = 1.0f;  // self-loop contributes 1 to every node's degree
}

__global__ void count_deg_kernel(const int* __restrict__ dst, int E,
                                 float* __restrict__ deg) {
    int e = blockIdx.x * blockDim.x + threadIdx.x;
    if (e < E) atomicAdd(&deg[dst[e]], 1.0f);
}

__global__ void finalize_dinv_kernel(float* __restrict__ deg, int n) {
    int i = blockIdx.x * blockDim.x + threadIdx.x;
    if (i < n) deg[i] = rsqrtf(deg[i]);  // deg >= 1 always (self-loops)
}

// out[row][col] = dinv[row] * sum_k X[row][k] * W[k][col]
// blockDim = ROWS_PER_BLOCK * COLS = 256; W staged in LDS (2-way bank alias = free),
// X rows staged in LDS (broadcast reads within each wave).
template <int K, int COLS, int ROWS_PER_BLOCK>
__global__ void gemm_scaled_kernel(const float* __restrict__ X,
                                   const float* __restrict__ W,
                                   const float* __restrict__ dinv,
                                   float* __restrict__ out, int n) {
    __shared__ float Ws[K * COLS];
    __shared__ float Xs[ROWS_PER_BLOCK][K];
    const int t = threadIdx.x;
    const int row0 = blockIdx.x * ROWS_PER_BLOCK;

    for (int i = t; i < K * COLS; i += blockDim.x) Ws[i] = W[i];
    for (int i = t; i < ROWS_PER_BLOCK * K; i += blockDim.x) {
        int r = row0 + i / K;
        Xs[i / K][i % K] = (r < n) ? X[(long long)r * K + (i % K)] : 0.0f;
    }
    __syncthreads();

    const int lr = t / COLS;        // wave-uniform (COLS == 64 == wave size)
    const int col = t % COLS;       // lane id
    const int row = row0 + lr;
    if (row >= n) return;

    float acc = 0.0f;
#pragma unroll
    for (int k = 0; k < K; ++k)
        acc = fmaf(Xs[lr][k], Ws[k * COLS + col], acc);

    out[(long long)row * COLS + col] = acc * dinv[row];
}

// One thread per (edge, channel). Within a wave: e is uniform, c = lane id,
// so the gather hs[s*64+c] and the atomic target out[d*64+c] are both
// 64 contiguous floats (fully coalesced 256B segments).
__global__ void scatter_edges_kernel(const int* __restrict__ src,
                                     const int* __restrict__ dst, int E,
                                     const float* __restrict__ hs,
                                     float* __restrict__ out) {
    int tid = blockIdx.x * blockDim.x + threadIdx.x;
    if (tid >= E * C_HID) return;
    int e = tid >> 6;
    int c = tid & 63;
    int s = src[e];
    int d = dst[e];
    atomicAdd(&out[d * C_HID + c], hs[s * C_HID + c]);
}

__global__ void finish_relu_kernel(float* __restrict__ buf,
                                   const float* __restrict__ dinv,
                                   const float* __restrict__ b, int n) {
    int i = blockIdx.x * blockDim.x + threadIdx.x;
    if (i >= n * C_HID) return;
    int v = i >> 6;
    int c = i & 63;
    float val = buf[i] * dinv[v] + b[c];
    buf[i] = fmaxf(val, 0.0f);
}

__global__ void finish_out_kernel(float* __restrict__ buf,
                                  const float* __restrict__ dinv,
                                  const float* __restrict__ b, int n) {
    int i = blockIdx.x * blockDim.x + threadIdx.x;
    if (i >= n * C_HID) return;
    int v = i >> 6;
    int c = i & 63;
    buf[i] = buf[i] * dinv[v] + b[c];
}

extern "C" void kernel_launch(void* const* d_in, const int* in_sizes, int n_in,
                              void* d_out, int out_size, void* d_ws, size_t ws_size,
                              hipStream_t stream) {
    const float* x  = (const float*)d_in[0];
    const int*   ei = (const int*)d_in[1];
    const float* W1 = (const float*)d_in[2];
    const float* b1 = (const float*)d_in[3];
    const float* W2 = (const float*)d_in[4];
    const float* b2 = (const float*)d_in[5];
    float* out = (float*)d_out;

    const int C_IN = 128;
    const int n = in_sizes[0] / C_IN;   // 50000
    const int E = in_sizes[1] / 2;      // 800000
    const int* src = ei;
    const int* dst = ei + E;

    // Workspace layout (~26 MB): dinv | A (n*64) | B (n*64)
    char* w = (char*)d_ws;
    float* dinv = (float*)w;  w += alignup((size_t)n * sizeof(float));
    float* A    = (float*)w;  w += alignup((size_t)n * C_HID * sizeof(float));
    float* B    = (float*)w;

    const int TB = 256;
    const size_t feat_bytes = (size_t)n * C_HID * sizeof(float);

    // 1) degree -> dinv
    init_deg_kernel<<<(n + TB - 1) / TB, TB, 0, stream>>>(dinv, n);
    count_deg_kernel<<<(E + TB - 1) / TB, TB, 0, stream>>>(dst, E, dinv);
    finalize_dinv_kernel<<<(n + TB - 1) / TB, TB, 0, stream>>>(dinv, n);

    // 2) layer 1: hs = (x @ W1) * dinv  -> A
    gemm_scaled_kernel<128, 64, 4><<<(n + 3) / 4, TB, 0, stream>>>(x, W1, dinv, A, n);

    // 3) aggregate: B = A (self-loop) + scatter of edges
    hipMemcpyAsync(B, A, feat_bytes, hipMemcpyDeviceToDevice, stream);
    {
        int total = E * C_HID;
        scatter_edges_kernel<<<(total + TB - 1) / TB, TB, 0, stream>>>(src, dst, E, A, B);
    }
    // 4) B = relu(B * dinv + b1)   (layer-2 input)
    finish_relu_kernel<<<(n * C_HID + TB - 1) / TB, TB, 0, stream>>>(B, dinv, b1, n);

    // 5) layer 2: hs2 = (B @ W2) * dinv -> A
    gemm_scaled_kernel<64, 64, 4><<<(n + 3) / 4, TB, 0, stream>>>(B, W2, dinv, A, n);

    // 6) aggregate into d_out
    hipMemcpyAsync(out, A, feat_bytes, hipMemcpyDeviceToDevice, stream);
    {
        int total = E * C_HID;
        scatter_edges_kernel<<<(total + TB - 1) / TB, TB, 0, stream>>>(src, dst, E, A, out);
    }
    // 7) d_out = d_out * dinv + b2
    finish_out_kernel<<<(n * C_HID + TB - 1) / TB, TB, 0, stream>>>(out, dinv, b2, n);
}

// Round 2
// 426.524 us; speedup vs baseline: 1.4475x; 1.4475x over previous
//
#include <hip/hip_runtime.h>

// GCN 2-layer forward, CSR pull-based aggregation (no float atomics).
// Layer: out[v] = dinv[v]*(hs[v] + sum_{e:dst=v} hs[src_e]) + b,  hs = (x@W)*dinv.

#define C_HID 64

static inline size_t alignup(size_t x) { return (x + 255) & ~(size_t)255; }

// ---------- degree / dinv ----------
__global__ void zero_int_kernel(int* __restrict__ p, int n) {
    int i = blockIdx.x * blockDim.x + threadIdx.x;
    if (i < n) p[i] = 0;
}

__global__ void count_deg_kernel(const int* __restrict__ dst, int E,
                                 int* __restrict__ deg) {
    int e = blockIdx.x * blockDim.x + threadIdx.x;
    if (e < E) atomicAdd(&deg[dst[e]], 1);
}

__global__ void dinv_kernel(const int* __restrict__ deg, float* __restrict__ dinv, int n) {
    int i = blockIdx.x * blockDim.x + threadIdx.x;
    if (i < n) dinv[i] = rsqrtf(1.0f + (float)deg[i]);  // +1 self-loop
}

// ---------- single-block streaming inclusive scan: row_ptr[0]=0, row_ptr[i+1]=sum(deg[0..i]) ----------
__global__ void scan_deg_kernel(const int* __restrict__ deg, int* __restrict__ row_ptr, int n) {
    __shared__ int smem[1024];
    int carry = 0;
    if (threadIdx.x == 0) row_ptr[0] = 0;
    for (int base = 0; base < n; base += 1024) {
        int i = base + threadIdx.x;
        int v = (i < n) ? deg[i] : 0;
        smem[threadIdx.x] = v;
        __syncthreads();
        for (int off = 1; off < 1024; off <<= 1) {
            int t = (threadIdx.x >= off) ? smem[threadIdx.x - off] : 0;
            __syncthreads();
            smem[threadIdx.x] += t;
            __syncthreads();
        }
        int incl = smem[threadIdx.x];
        if (i < n) row_ptr[i + 1] = incl + carry;
        carry += smem[1023];
        __syncthreads();   // protect smem before next chunk overwrites
    }
}

// ---------- bucket edges by dst ----------
__global__ void place_edges_kernel(const int* __restrict__ src,
                                   const int* __restrict__ dst, int E,
                                   int* __restrict__ cursor,
                                   int* __restrict__ esrc) {
    int e = blockIdx.x * blockDim.x + threadIdx.x;
    if (e >= E) return;
    int d = dst[e];
    int pos = atomicAdd(&cursor[d], 1);
    esrc[pos] = src[e];
}

// ---------- LDS-free GEMM: out[r][c] = dinv[r] * sum_k X[r][k]*W[k][c] ----------
// One wave per row-group: lane = output column, W column held in VGPRs,
// X row read via wave-uniform (scalar) loads.
template <int K>
__global__ __launch_bounds__(256) void gemm_regW_kernel(
    const float* __restrict__ X, const float* __restrict__ W,
    const float* __restrict__ dinv, float* __restrict__ out, int n) {
    const int lane = threadIdx.x & 63;
    const int wavesPerBlock = blockDim.x >> 6;
    const int wid = blockIdx.x * wavesPerBlock + (threadIdx.x >> 6);
    const int nWaves = gridDim.x * wavesPerBlock;

    float Wreg[K];
#pragma unroll
    for (int k = 0; k < K; ++k) Wreg[k] = W[k * 64 + lane];

    for (int r = wid; r < n; r += nWaves) {
        const int ru = __builtin_amdgcn_readfirstlane(r);   // force SGPR -> s_load for X row
        const float* xr = X + (size_t)ru * K;
        float acc = 0.0f;
#pragma unroll
        for (int k = 0; k < K; ++k) acc = fmaf(xr[k], Wreg[k], acc);
        out[(size_t)ru * 64 + lane] = acc * dinv[ru];
    }
}

// ---------- pull aggregation: one wave per node ----------
template <bool RELU>
__global__ void aggregate_kernel(const float* __restrict__ hs,
                                 const int* __restrict__ row_ptr,
                                 const int* __restrict__ esrc,
                                 const float* __restrict__ dinv,
                                 const float* __restrict__ bias,
                                 float* __restrict__ out, int n) {
    const int v = blockIdx.x * (blockDim.x >> 6) + (threadIdx.x >> 6);
    if (v >= n) return;
    const int lane = threadIdx.x & 63;
    const int beg = row_ptr[v];
    const int end = row_ptr[v + 1];

    float acc = hs[(size_t)v * C_HID + lane];   // self-loop term
    for (int j = beg; j < end; j += 64) {
        const int cnt = min(64, end - j);
        int eid = (j + lane < end) ? esrc[j + lane] : 0;   // coalesced edge-id load
#pragma unroll 4
        for (int i = 0; i < cnt; ++i) {
            int s = __shfl(eid, i);
            acc += hs[(size_t)s * C_HID + lane];           // coalesced 256B row gather
        }
    }
    float val = acc * dinv[v] + bias[lane];
    if (RELU) val = fmaxf(val, 0.0f);
    out[(size_t)v * C_HID + lane] = val;
}

extern "C" void kernel_launch(void* const* d_in, const int* in_sizes, int n_in,
                              void* d_out, int out_size, void* d_ws, size_t ws_size,
                              hipStream_t stream) {
    const float* x  = (const float*)d_in[0];
    const int*   ei = (const int*)d_in[1];
    const float* W1 = (const float*)d_in[2];
    const float* b1 = (const float*)d_in[3];
    const float* W2 = (const float*)d_in[4];
    const float* b2 = (const float*)d_in[5];
    float* out = (float*)d_out;

    const int C_IN = 128;
    const int n = in_sizes[0] / C_IN;   // 50000
    const int E = in_sizes[1] / 2;      // 800000
    const int* src = ei;
    const int* dst = ei + E;

    // Workspace: dinv | A | B | deg | row_ptr | cursor | esrc   (~30 MB)
    char* w = (char*)d_ws;
    float* dinv    = (float*)w; w += alignup((size_t)n * sizeof(float));
    float* A       = (float*)w; w += alignup((size_t)n * C_HID * sizeof(float));
    float* B       = (float*)w; w += alignup((size_t)n * C_HID * sizeof(float));
    int*   deg     = (int*)w;   w += alignup((size_t)n * sizeof(int));
    int*   row_ptr = (int*)w;   w += alignup((size_t)(n + 1) * sizeof(int));
    int*   cursor  = (int*)w;   w += alignup((size_t)n * sizeof(int));
    int*   esrc    = (int*)w;

    const int TB = 256;

    // 1) CSR build (shared by both layers)
    zero_int_kernel<<<(n + TB - 1) / TB, TB, 0, stream>>>(deg, n);
    count_deg_kernel<<<(E + TB - 1) / TB, TB, 0, stream>>>(dst, E, deg);
    dinv_kernel<<<(n + TB - 1) / TB, TB, 0, stream>>>(deg, dinv, n);
    scan_deg_kernel<<<1, 1024, 0, stream>>>(deg, row_ptr, n);
    hipMemcpyAsync(cursor, row_ptr, (size_t)n * sizeof(int),
                   hipMemcpyDeviceToDevice, stream);
    place_edges_kernel<<<(E + TB - 1) / TB, TB, 0, stream>>>(src, dst, E, cursor, esrc);

    // 2) layer 1
    gemm_regW_kernel<128><<<1024, 256, 0, stream>>>(x, W1, dinv, A, n);
    aggregate_kernel<true><<<(n + 3) / 4, 256, 0, stream>>>(A, row_ptr, esrc, dinv, b1, B, n);

    // 3) layer 2
    gemm_regW_kernel<64><<<1024, 256, 0, stream>>>(B, W2, dinv, A, n);
    aggregate_kernel<false><<<(n + 3) / 4, 256, 0, stream>>>(A, row_ptr, esrc, dinv, b2, out, n);
}

// Round 3
// 303.653 us; speedup vs baseline: 2.0333x; 1.4046x over previous
//
#include <hip/hip_runtime.h>

// GCN 2-layer forward, CSR pull-based aggregation (no float atomics).
// Layer: out[v] = dinv[v]*(hs[v] + sum_{e:dst=v} hs[src_e]) + b,  hs = (x@W)*dinv.

#define C_HID 64
#define CHUNK 1024   // elements per scan block; supports n <= 64*1024

static inline size_t alignup(size_t x) { return (x + 255) & ~(size_t)255; }

// ---------- degree ----------
__global__ void count_deg_kernel(const int* __restrict__ dst, int E,
                                 int* __restrict__ deg) {
    int e = blockIdx.x * blockDim.x + threadIdx.x;
    if (e < E) atomicAdd(&deg[dst[e]], 1);
}

// ---------- hierarchical scan, stage A: per-block sums ----------
__global__ __launch_bounds__(CHUNK) void block_sums_kernel(
    const int* __restrict__ deg, int* __restrict__ bsum, int n) {
    __shared__ int wsum[CHUNK / 64];
    int i = blockIdx.x * CHUNK + threadIdx.x;
    int v = (i < n) ? deg[i] : 0;
#pragma unroll
    for (int off = 32; off; off >>= 1) v += __shfl_down(v, off);
    int lane = threadIdx.x & 63, wav = threadIdx.x >> 6;
    if (lane == 0) wsum[wav] = v;
    __syncthreads();
    if (threadIdx.x == 0) {
        int t = 0;
#pragma unroll
        for (int w2 = 0; w2 < CHUNK / 64; ++w2) t += wsum[w2];
        bsum[blockIdx.x] = t;
    }
}

// ---------- stage B: exclusive scan of block sums (nb <= 64, one wave) ----------
__global__ void scan_bsums_kernel(int* __restrict__ bsum, int nb) {
    int lane = threadIdx.x;
    int v = (lane < nb) ? bsum[lane] : 0;
    int s = v;
#pragma unroll
    for (int off = 1; off < 64; off <<= 1) {
        int t = __shfl_up(s, off);
        if (lane >= off) s += t;
    }
    if (lane < nb) bsum[lane] = s - v;   // exclusive prefix
}

// ---------- stage C: local scan + offset; emit row_ptr, cursor, dinv ----------
__global__ __launch_bounds__(CHUNK) void scan_chunks_kernel(
    const int* __restrict__ deg, const int* __restrict__ blkoff,
    int* __restrict__ row_ptr, int* __restrict__ cursor,
    float* __restrict__ dinv, int n) {
    __shared__ int wsum[CHUNK / 64];
    int i = blockIdx.x * CHUNK + threadIdx.x;
    int v = (i < n) ? deg[i] : 0;
    int lane = threadIdx.x & 63, wav = threadIdx.x >> 6;
    int s = v;
#pragma unroll
    for (int off = 1; off < 64; off <<= 1) {
        int t = __shfl_up(s, off);
        if (lane >= off) s += t;
    }
    if (lane == 63) wsum[wav] = s;
    __syncthreads();
    if (wav == 0) {
        int ws = (lane < CHUNK / 64) ? wsum[lane] : 0;
#pragma unroll
        for (int off = 1; off < CHUNK / 64; off <<= 1) {
            int t = __shfl_up(ws, off);
            if (lane >= off) ws += t;
        }
        if (lane < CHUNK / 64) wsum[lane] = ws;
    }
    __syncthreads();
    int base = blkoff[blockIdx.x] + (wav > 0 ? wsum[wav - 1] : 0);
    int incl = base + s;
    if (i < n) {
        row_ptr[i + 1] = incl;
        cursor[i] = incl - v;                    // exclusive prefix = bucket start
        dinv[i] = rsqrtf(1.0f + (float)v);       // +1 self-loop
    }
    if (i == 0) row_ptr[0] = 0;
}

// ---------- bucket edges by dst ----------
__global__ void place_edges_kernel(const int* __restrict__ src,
                                   const int* __restrict__ dst, int E,
                                   int* __restrict__ cursor,
                                   int* __restrict__ esrc) {
    int e = blockIdx.x * blockDim.x + threadIdx.x;
    if (e >= E) return;
    int d = dst[e];
    int pos = atomicAdd(&cursor[d], 1);
    esrc[pos] = src[e];
}

// ---------- LDS-free GEMM: out[r][c] = dinv[r] * sum_k X[r][k]*W[k][c] ----------
template <int K>
__global__ __launch_bounds__(256) void gemm_regW_kernel(
    const float* __restrict__ X, const float* __restrict__ W,
    const float* __restrict__ dinv, float* __restrict__ out, int n) {
    const int lane = threadIdx.x & 63;
    const int wavesPerBlock = blockDim.x >> 6;
    const int wid = blockIdx.x * wavesPerBlock + (threadIdx.x >> 6);
    const int nWaves = gridDim.x * wavesPerBlock;

    float Wreg[K];
#pragma unroll
    for (int k = 0; k < K; ++k) Wreg[k] = W[k * 64 + lane];

    for (int r = wid; r < n; r += nWaves) {
        const int ru = __builtin_amdgcn_readfirstlane(r);   // SGPR row -> s_load for X row
        const float* xr = X + (size_t)ru * K;
        float acc = 0.0f;
#pragma unroll
        for (int k = 0; k < K; ++k) acc = fmaf(xr[k], Wreg[k], acc);
        out[(size_t)ru * 64 + lane] = acc * dinv[ru];
    }
}

// ---------- pull aggregation: one wave per node, 4 edges per inner iter ----------
// lane -> sub = lane>>4 (which edge), c4 = lane&15 (float4 channel group).
template <bool RELU>
__global__ void aggregate4_kernel(const float* __restrict__ hs,
                                  const int* __restrict__ row_ptr,
                                  const int* __restrict__ esrc,
                                  const float* __restrict__ dinv,
                                  const float* __restrict__ bias,
                                  float* __restrict__ out, int n) {
    const int v = blockIdx.x * (blockDim.x >> 6) + (threadIdx.x >> 6);
    if (v >= n) return;
    const int lane = threadIdx.x & 63;
    const int sub = lane >> 4;      // 0..3: which concurrent edge
    const int c4 = lane & 15;       // float4 index within a 64-float row
    const float4* __restrict__ hs4 = (const float4*)hs;

    const int beg = row_ptr[v];
    const int end = row_ptr[v + 1];

    float4 acc = make_float4(0.f, 0.f, 0.f, 0.f);
    if (sub == 0) acc = hs4[(size_t)v * 16 + c4];   // self-loop term, once

    for (int j = beg; j < end; j += 64) {
        const int cnt = min(64, end - j);
        int eid = (j + lane < end) ? esrc[j + lane] : 0;   // coalesced edge ids
        for (int i = 0; i < cnt; i += 4) {
            int idx = i + sub;
            int s = __shfl(eid, idx < cnt ? idx : 0);
            if (idx < cnt) {
                float4 r = hs4[(size_t)s * 16 + c4];       // 4 rows x 256B per wave-iter
                acc.x += r.x; acc.y += r.y; acc.z += r.z; acc.w += r.w;
            }
        }
    }

    // reduce the 4 sub-accumulators (lanes differing in bits 4-5)
#pragma unroll
    for (int m = 16; m < 64; m <<= 1) {
        acc.x += __shfl_xor(acc.x, m);
        acc.y += __shfl_xor(acc.y, m);
        acc.z += __shfl_xor(acc.z, m);
        acc.w += __shfl_xor(acc.w, m);
    }

    if (sub == 0) {
        float dv = dinv[v];
        float4 b4 = ((const float4*)bias)[c4];
        float4 r;
        r.x = acc.x * dv + b4.x;
        r.y = acc.y * dv + b4.y;
        r.z = acc.z * dv + b4.z;
        r.w = acc.w * dv + b4.w;
        if (RELU) {
            r.x = fmaxf(r.x, 0.f); r.y = fmaxf(r.y, 0.f);
            r.z = fmaxf(r.z, 0.f); r.w = fmaxf(r.w, 0.f);
        }
        ((float4*)out)[(size_t)v * 16 + c4] = r;
    }
}

extern "C" void kernel_launch(void* const* d_in, const int* in_sizes, int n_in,
                              void* d_out, int out_size, void* d_ws, size_t ws_size,
                              hipStream_t stream) {
    const float* x  = (const float*)d_in[0];
    const int*   ei = (const int*)d_in[1];
    const float* W1 = (const float*)d_in[2];
    const float* b1 = (const float*)d_in[3];
    const float* W2 = (const float*)d_in[4];
    const float* b2 = (const float*)d_in[5];
    float* out = (float*)d_out;

    const int C_IN = 128;
    const int n = in_sizes[0] / C_IN;   // 50000
    const int E = in_sizes[1] / 2;      // 800000
    const int* src = ei;
    const int* dst = ei + E;

    // Workspace: dinv | A | B | deg | row_ptr | cursor | bsum | esrc  (~30 MB)
    char* w = (char*)d_ws;
    float* dinv    = (float*)w; w += alignup((size_t)n * sizeof(float));
    float* A       = (float*)w; w += alignup((size_t)n * C_HID * sizeof(float));
    float* B       = (float*)w; w += alignup((size_t)n * C_HID * sizeof(float));
    int*   deg     = (int*)w;   w += alignup((size_t)n * sizeof(int));
    int*   row_ptr = (int*)w;   w += alignup((size_t)(n + 1) * sizeof(int));
    int*   cursor  = (int*)w;   w += alignup((size_t)n * sizeof(int));
    int*   bsum    = (int*)w;   w += alignup(64 * sizeof(int));
    int*   esrc    = (int*)w;

    const int TB = 256;
    const int NB = (n + CHUNK - 1) / CHUNK;   // 49 blocks (<= 64 required)

    // 1) CSR build
    hipMemsetAsync(deg, 0, (size_t)n * sizeof(int), stream);
    count_deg_kernel<<<(E + TB - 1) / TB, TB, 0, stream>>>(dst, E, deg);
    block_sums_kernel<<<NB, CHUNK, 0, stream>>>(deg, bsum, n);
    scan_bsums_kernel<<<1, 64, 0, stream>>>(bsum, NB);
    scan_chunks_kernel<<<NB, CHUNK, 0, stream>>>(deg, bsum, row_ptr, cursor, dinv, n);
    place_edges_kernel<<<(E + TB - 1) / TB, TB, 0, stream>>>(src, dst, E, cursor, esrc);

    // 2) layer 1
    gemm_regW_kernel<128><<<1024, 256, 0, stream>>>(x, W1, dinv, A, n);
    aggregate4_kernel<true><<<(n + 3) / 4, 256, 0, stream>>>(A, row_ptr, esrc, dinv, b1, B, n);

    // 3) layer 2
    gemm_regW_kernel<64><<<1024, 256, 0, stream>>>(B, W2, dinv, A, n);
    aggregate4_kernel<false><<<(n + 3) / 4, 256, 0, stream>>>(A, row_ptr, esrc, dinv, b2, out, n);
}